// Round 1
// baseline (7287.843 us; speedup 1.0000x reference)
//
#include <hip/hip_runtime.h>
#include <stdint.h>

// GRU: T=1024, B=64, F=256, H=512, 3H=1536, M=T*B=65536
// ws layout (bytes):
//   xg  bf16 [65536][1536] @ 0          (201,326,592)
//   xbf bf16 [65536][256]  @ 201326592  (33,554,432)
//   wit bf16 [1536][256]   @ 234881024  (786,432)     = Wi^T
//   wht bf16 [1536][512]   @ 235667456  (1,572,864)   = Wh^T
//   hbf bf16 [2][64][512]  @ 237240320  (131,072)     double-buffered h
//   ctr u32                @ 237371392
#define NB 32  // scan blocks; must all be co-resident (32 << 256 CUs)

typedef __attribute__((ext_vector_type(8))) short short8;
typedef __attribute__((ext_vector_type(4))) float floatx4;

__device__ __forceinline__ unsigned short f2bf(float f) {
  unsigned u = __float_as_uint(f);
  u += 0x7fff + ((u >> 16) & 1);  // RNE
  return (unsigned short)(u >> 16);
}
__device__ __forceinline__ float bf2f(unsigned short s) {
  return __uint_as_float(((unsigned)s) << 16);
}

// ---------------- prep: casts + transposes + init ----------------
__global__ __launch_bounds__(256) void prep_kernel(
    const float* __restrict__ x, const float* __restrict__ h0,
    const float* __restrict__ Wi, const float* __restrict__ Wh,
    unsigned short* __restrict__ xbf, unsigned short* __restrict__ wit,
    unsigned short* __restrict__ wht, unsigned short* __restrict__ hbf,
    unsigned int* __restrict__ ctr) {
  int i = blockIdx.x * 256 + threadIdx.x;
  if (i < 4194304) {                       // x cast, 4 elems/thread
    float4 v = ((const float4*)x)[i];
    ushort4 o;
    o.x = f2bf(v.x); o.y = f2bf(v.y); o.z = f2bf(v.z); o.w = f2bf(v.w);
    ((ushort4*)xbf)[i] = o;
  } else if (i < 4587520) {                // Wi^T: wit[n*256+k] = Wi[k*1536+n]
    int j = i - 4194304;
    int n = j >> 8, k = j & 255;
    wit[j] = f2bf(Wi[(size_t)k * 1536 + n]);
  } else if (i < 5373952) {                // Wh^T: wht[n*512+k] = Wh[k*1536+n]
    int j = i - 4587520;
    int n = j >> 9, k = j & 511;
    wht[j] = f2bf(Wh[(size_t)k * 1536 + n]);
  } else if (i < 5406720) {                // h_bf[0] = bf16(h0)
    int j = i - 5373952;
    hbf[j] = f2bf(h0[j]);
  } else if (i == 5406720) {
    *ctr = 0u;
  }
}

// ---------------- xg = x @ Wi + bi (bf16 MFMA, 128x128 tile) ----------------
__global__ __launch_bounds__(256, 2) void gemm_xg(
    const unsigned short* __restrict__ A,   // [65536][256] bf16
    const unsigned short* __restrict__ BT,  // [1536][256] bf16 (Wi^T)
    const float* __restrict__ bi,
    unsigned short* __restrict__ C) {       // [65536][1536] bf16
  __shared__ __align__(16) unsigned short lA[128 * 72];  // +8 pad: bank-conflict-free
  __shared__ __align__(16) unsigned short lB[128 * 72];
  const int tid = threadIdx.x;
  const int w = tid >> 6, lane = tid & 63;
  const int wm = w >> 1, wn = w & 1;
  const int q = lane >> 4, l16 = lane & 15;
  const int bx = blockIdx.x, by = blockIdx.y;

  floatx4 acc[4][4];
#pragma unroll
  for (int a = 0; a < 4; ++a)
#pragma unroll
    for (int b = 0; b < 4; ++b) acc[a][b] = (floatx4){0.f, 0.f, 0.f, 0.f};

  for (int kt = 0; kt < 4; ++kt) {   // K=256 in BK=64 chunks
    if (kt) __syncthreads();
#pragma unroll
    for (int i = 0; i < 4; ++i) {    // stage A,B tiles (16B/lane vec loads)
      int c = tid + i * 256;
      int r = c >> 3, kk = (c & 7) * 8;
      *(uint4*)&lA[r * 72 + kk] =
          *(const uint4*)&A[(size_t)(bx * 128 + r) * 256 + kt * 64 + kk];
      *(uint4*)&lB[r * 72 + kk] =
          *(const uint4*)&BT[(size_t)(by * 128 + r) * 256 + kt * 64 + kk];
    }
    __syncthreads();
#pragma unroll
    for (int ks = 0; ks < 2; ++ks) {
      const int kk = ks * 32 + q * 8;
      short8 af[4], bf[4];
#pragma unroll
      for (int rm = 0; rm < 4; ++rm)
        af[rm] = *(const short8*)&lA[(wm * 64 + rm * 16 + l16) * 72 + kk];
#pragma unroll
      for (int cn = 0; cn < 4; ++cn)
        bf[cn] = *(const short8*)&lB[(wn * 64 + cn * 16 + l16) * 72 + kk];
#pragma unroll
      for (int rm = 0; rm < 4; ++rm)
#pragma unroll
        for (int cn = 0; cn < 4; ++cn)
          acc[rm][cn] = __builtin_amdgcn_mfma_f32_16x16x32_bf16(
              af[rm], bf[cn], acc[rm][cn], 0, 0, 0);
    }
  }
  // epilogue: + bi, store bf16. C layout: col=lane&15, row=q*4+reg
#pragma unroll
  for (int cn = 0; cn < 4; ++cn) {
    const int col = by * 128 + wn * 64 + cn * 16 + l16;
    const float bic = bi[col];
#pragma unroll
    for (int rm = 0; rm < 4; ++rm)
#pragma unroll
      for (int r = 0; r < 4; ++r) {
        const int row = bx * 128 + wm * 64 + rm * 16 + q * 4 + r;
        C[(size_t)row * 1536 + col] = f2bf(acc[rm][cn][r] + bic);
      }
  }
}

// ---------------- persistent GRU scan ----------------
// 32 blocks x 256 thr. Block b owns h dims [b*16, b*16+16).
// Wh^T b-frags live in registers (192 VGPRs, loop-invariant).
// Per-lane h master stays in fp32 registers (same (batch,dim) every step).
__global__ __launch_bounds__(256, 1) void scan_kernel(
    const unsigned short* __restrict__ xg,   // [T*B][1536] bf16
    const unsigned short* __restrict__ wht,  // [1536][512] bf16
    const float* __restrict__ h0, const float* __restrict__ bhn,
    float* __restrict__ ys,                  // [T*B][512] f32
    unsigned short* __restrict__ hbf,        // [2][64][512] bf16
    unsigned int* __restrict__ ctr) {
  const int tid = threadIdx.x;
  const int w = tid >> 6, lane = tid & 63;
  const int q = lane >> 4, l16 = lane & 15;
  const int i0 = blockIdx.x * 16;

  // b-frags: lane holds B[k=q*8+j][n=l16] = wht[n][k], 8 consecutive k
  short8 bfr[3][16];
#pragma unroll
  for (int g = 0; g < 3; ++g)
#pragma unroll
    for (int s = 0; s < 16; ++s)
      bfr[g][s] = *(const short8*)
          &wht[(size_t)(g * 512 + i0 + l16) * 512 + s * 32 + q * 8];

  const int dim = i0 + l16;        // C-layout col
  const float bhn_c = bhn[dim];
  const int bc0 = w * 16 + q * 4;  // C-layout rows (batches) bc0..bc0+3
  const int ba = w * 16 + l16;     // A-frag row (batch)

  float hreg[4];
#pragma unroll
  for (int r = 0; r < 4; ++r) hreg[r] = h0[(size_t)(bc0 + r) * 512 + dim];

  float xgv[3][4];                 // step-t xg values (prefetched)
#pragma unroll
  for (int r = 0; r < 4; ++r) {
    size_t xb = (size_t)(bc0 + r) * 1536 + dim;
    xgv[0][r] = bf2f(xg[xb]);
    xgv[1][r] = bf2f(xg[xb + 512]);
    xgv[2][r] = bf2f(xg[xb + 1024]);
  }

  for (int t = 0; t < 1024; ++t) {
    const unsigned short* hsrc = hbf + (size_t)(t & 1) * 32768;
    unsigned short* hdst = hbf + (size_t)((t + 1) & 1) * 32768;

    // A-frags: lane holds A[m=l16][k=q*8+j], 16 k-steps covering K=512
    short8 af[16];
#pragma unroll
    for (int s = 0; s < 16; ++s)
      af[s] = *(const short8*)&hsrc[(size_t)ba * 512 + s * 32 + q * 8];

    floatx4 a0 = {0.f, 0.f, 0.f, 0.f};
    floatx4 a1 = {0.f, 0.f, 0.f, 0.f};
    floatx4 a2 = {0.f, 0.f, 0.f, 0.f};
#pragma unroll
    for (int s = 0; s < 16; ++s) {
      a0 = __builtin_amdgcn_mfma_f32_16x16x32_bf16(af[s], bfr[0][s], a0, 0, 0, 0);
      a1 = __builtin_amdgcn_mfma_f32_16x16x32_bf16(af[s], bfr[1][s], a1, 0, 0, 0);
      a2 = __builtin_amdgcn_mfma_f32_16x16x32_bf16(af[s], bfr[2][s], a2, 0, 0, 0);
    }

#pragma unroll
    for (int r = 0; r < 4; ++r) {
      const int bc = bc0 + r;
      float rg = 1.f / (1.f + __expf(-(xgv[0][r] + a0[r])));
      float zg = 1.f / (1.f + __expf(-(xgv[1][r] + a1[r])));
      float pre = xgv[2][r] + rg * (a2[r] + bhn_c);
      pre = fminf(fmaxf(pre, -15.f), 15.f);  // avoid inf/inf NaN in tanh
      float e2 = __expf(2.f * pre);
      float ng = (e2 - 1.f) / (e2 + 1.f);
      float hnew = (1.f - zg) * ng + zg * hreg[r];
      hreg[r] = hnew;
      ys[((size_t)t * 64 + bc) * 512 + dim] = hnew;
      hdst[(size_t)bc * 512 + dim] = f2bf(hnew);
    }

    if (t != 1023) {
      // prefetch next-step xg: no h dependence, hides behind the barrier
#pragma unroll
      for (int r = 0; r < 4; ++r) {
        size_t xb = ((size_t)(t + 1) * 64 + bc0 + r) * 1536 + dim;
        xgv[0][r] = bf2f(xg[xb]);
        xgv[1][r] = bf2f(xg[xb + 512]);
        xgv[2][r] = bf2f(xg[xb + 1024]);
      }
      __syncthreads();  // drains vmcnt: all stores in L2 (write-through L1)
      if (tid == 0) {
        __threadfence();                 // agent release: L2 -> LLC writeback
        atomicAdd(ctr, 1u);              // device-scope, monotonic counter
        const unsigned tgt = (unsigned)NB * (unsigned)(t + 1);
        while (__hip_atomic_load(ctr, __ATOMIC_RELAXED,
                                 __HIP_MEMORY_SCOPE_AGENT) < tgt) {}
        __threadfence();                 // agent acquire: L1/L2 invalidate
      }
      __syncthreads();
    }
  }
}

extern "C" void kernel_launch(void* const* d_in, const int* in_sizes, int n_in,
                              void* d_out, int out_size, void* d_ws, size_t ws_size,
                              hipStream_t stream) {
  const float* x   = (const float*)d_in[0];
  const float* h0  = (const float*)d_in[1];
  const float* Wi  = (const float*)d_in[2];
  const float* bi  = (const float*)d_in[3];
  const float* Wh  = (const float*)d_in[4];
  const float* bhn = (const float*)d_in[5];
  float* ys = (float*)d_out;

  char* ws = (char*)d_ws;
  unsigned short* xg  = (unsigned short*)(ws);
  unsigned short* xbf = (unsigned short*)(ws + 201326592);
  unsigned short* wit = (unsigned short*)(ws + 234881024);
  unsigned short* wht = (unsigned short*)(ws + 235667456);
  unsigned short* hbf = (unsigned short*)(ws + 237240320);
  unsigned int*   ctr = (unsigned int*)(ws + 237371392);

  prep_kernel<<<21121, 256, 0, stream>>>(x, h0, Wi, Wh, xbf, wit, wht, hbf, ctr);
  gemm_xg<<<dim3(512, 12), 256, 0, stream>>>(xbf, wit, bi, xg);
  scan_kernel<<<NB, 256, 0, stream>>>(xg, wht, h0, bhn, ys, hbf, ctr);
}

// Round 2
// 6119.086 us; speedup vs baseline: 1.1910x; 1.1910x over previous
//
#include <hip/hip_runtime.h>
#include <stdint.h>

// GRU: T=1024, B=64, F=256, H=512, 3H=1536, M=T*B=65536
// ws layout (bytes):
//   xg  bf16 [65536][1536] @ 0          (201,326,592)
//   xbf bf16 [65536][256]  @ 201326592  (33,554,432)
//   wit bf16 [1536][256]   @ 234881024  (786,432)     = Wi^T
//   wht bf16 [1536][512]   @ 235667456  (1,572,864)   = Wh^T
//   hbf bf16 [2][64][512]  @ 237240320  (131,072)     double-buffered h
//   ctr u32                @ 237371392
#define NB 32  // scan blocks; must all be co-resident (32 << 256 CUs)

typedef __attribute__((ext_vector_type(8))) short short8;
typedef __attribute__((ext_vector_type(4))) float floatx4;

__device__ __forceinline__ unsigned short f2bf(float f) {
  unsigned u = __float_as_uint(f);
  u += 0x7fff + ((u >> 16) & 1);  // RNE
  return (unsigned short)(u >> 16);
}
__device__ __forceinline__ float bf2f(unsigned short s) {
  return __uint_as_float(((unsigned)s) << 16);
}

// Agent-scope (LLC-coherent, L1/L2-bypass) 16B fragment load: two relaxed
// 64-bit atomic loads (global_load_dwordx2 sc1). No cache-wide inv needed.
__device__ __forceinline__ short8 load_frag_agent(const unsigned short* p) {
  union { unsigned long long u[2]; short8 s; } v;
  v.u[0] = __hip_atomic_load((const unsigned long long*)p,
                             __ATOMIC_RELAXED, __HIP_MEMORY_SCOPE_AGENT);
  v.u[1] = __hip_atomic_load((const unsigned long long*)(p + 4),
                             __ATOMIC_RELAXED, __HIP_MEMORY_SCOPE_AGENT);
  return v.s;
}

// ---------------- prep: casts + transposes + init ----------------
__global__ __launch_bounds__(256) void prep_kernel(
    const float* __restrict__ x, const float* __restrict__ h0,
    const float* __restrict__ Wi, const float* __restrict__ Wh,
    unsigned short* __restrict__ xbf, unsigned short* __restrict__ wit,
    unsigned short* __restrict__ wht, unsigned short* __restrict__ hbf,
    unsigned int* __restrict__ ctr) {
  int i = blockIdx.x * 256 + threadIdx.x;
  if (i < 4194304) {                       // x cast, 4 elems/thread
    float4 v = ((const float4*)x)[i];
    ushort4 o;
    o.x = f2bf(v.x); o.y = f2bf(v.y); o.z = f2bf(v.z); o.w = f2bf(v.w);
    ((ushort4*)xbf)[i] = o;
  } else if (i < 4587520) {                // Wi^T: wit[n*256+k] = Wi[k*1536+n]
    int j = i - 4194304;
    int n = j >> 8, k = j & 255;
    wit[j] = f2bf(Wi[(size_t)k * 1536 + n]);
  } else if (i < 5373952) {                // Wh^T: wht[n*512+k] = Wh[k*1536+n]
    int j = i - 4587520;
    int n = j >> 9, k = j & 511;
    wht[j] = f2bf(Wh[(size_t)k * 1536 + n]);
  } else if (i < 5406720) {                // h_bf[0] = bf16(h0), agent-visible
    int j = i - 5373952;
    __hip_atomic_store(&hbf[j], f2bf(h0[j]),
                       __ATOMIC_RELAXED, __HIP_MEMORY_SCOPE_AGENT);
  } else if (i == 5406720) {
    __hip_atomic_store(ctr, 0u, __ATOMIC_RELAXED, __HIP_MEMORY_SCOPE_AGENT);
  }
}

// ---------------- xg = x @ Wi + bi (bf16 MFMA, 128x128 tile) ----------------
__global__ __launch_bounds__(256, 2) void gemm_xg(
    const unsigned short* __restrict__ A,   // [65536][256] bf16
    const unsigned short* __restrict__ BT,  // [1536][256] bf16 (Wi^T)
    const float* __restrict__ bi,
    unsigned short* __restrict__ C) {       // [65536][1536] bf16
  __shared__ __align__(16) unsigned short lA[128 * 72];  // +8 pad
  __shared__ __align__(16) unsigned short lB[128 * 72];
  const int tid = threadIdx.x;
  const int w = tid >> 6, lane = tid & 63;
  const int wm = w >> 1, wn = w & 1;
  const int q = lane >> 4, l16 = lane & 15;
  const int bx = blockIdx.x, by = blockIdx.y;

  floatx4 acc[4][4];
#pragma unroll
  for (int a = 0; a < 4; ++a)
#pragma unroll
    for (int b = 0; b < 4; ++b) acc[a][b] = (floatx4){0.f, 0.f, 0.f, 0.f};

  for (int kt = 0; kt < 4; ++kt) {   // K=256 in BK=64 chunks
    if (kt) __syncthreads();
#pragma unroll
    for (int i = 0; i < 4; ++i) {    // stage A,B tiles (16B/lane vec loads)
      int c = tid + i * 256;
      int r = c >> 3, kk = (c & 7) * 8;
      *(uint4*)&lA[r * 72 + kk] =
          *(const uint4*)&A[(size_t)(bx * 128 + r) * 256 + kt * 64 + kk];
      *(uint4*)&lB[r * 72 + kk] =
          *(const uint4*)&BT[(size_t)(by * 128 + r) * 256 + kt * 64 + kk];
    }
    __syncthreads();
#pragma unroll
    for (int ks = 0; ks < 2; ++ks) {
      const int kk = ks * 32 + q * 8;
      short8 af[4], bf[4];
#pragma unroll
      for (int rm = 0; rm < 4; ++rm)
        af[rm] = *(const short8*)&lA[(wm * 64 + rm * 16 + l16) * 72 + kk];
#pragma unroll
      for (int cn = 0; cn < 4; ++cn)
        bf[cn] = *(const short8*)&lB[(wn * 64 + cn * 16 + l16) * 72 + kk];
#pragma unroll
      for (int rm = 0; rm < 4; ++rm)
#pragma unroll
        for (int cn = 0; cn < 4; ++cn)
          acc[rm][cn] = __builtin_amdgcn_mfma_f32_16x16x32_bf16(
              af[rm], bf[cn], acc[rm][cn], 0, 0, 0);
    }
  }
  // epilogue: + bi, store bf16. C layout: col=lane&15, row=q*4+reg
#pragma unroll
  for (int cn = 0; cn < 4; ++cn) {
    const int col = by * 128 + wn * 64 + cn * 16 + l16;
    const float bic = bi[col];
#pragma unroll
    for (int rm = 0; rm < 4; ++rm)
#pragma unroll
      for (int r = 0; r < 4; ++r) {
        const int row = bx * 128 + wm * 64 + rm * 16 + q * 4 + r;
        C[(size_t)row * 1536 + col] = f2bf(acc[rm][cn][r] + bic);
      }
  }
}

// ---------------- persistent GRU scan ----------------
// 32 blocks x 256 thr. Block b owns h dims [b*16, b*16+16).
// Wh^T b-frags live in registers (192 VGPRs, loop-invariant).
// h master stays in fp32 registers; cross-block h exchange goes through the
// LLC via agent-scope (sc1) loads/stores — NO cache-wide wb/inv fences.
__global__ __launch_bounds__(256, 1) void scan_kernel(
    const unsigned short* __restrict__ xg,   // [T*B][1536] bf16
    const unsigned short* __restrict__ wht,  // [1536][512] bf16
    const float* __restrict__ h0, const float* __restrict__ bhn,
    float* __restrict__ ys,                  // [T*B][512] f32
    unsigned short* __restrict__ hbf,        // [2][64][512] bf16
    unsigned int* __restrict__ ctr) {
  const int tid = threadIdx.x;
  const int w = tid >> 6, lane = tid & 63;
  const int q = lane >> 4, l16 = lane & 15;
  const int i0 = blockIdx.x * 16;

  // b-frags: lane holds B[k=q*8+j][n=l16] = wht[n][k], 8 consecutive k
  short8 bfr[3][16];
#pragma unroll
  for (int g = 0; g < 3; ++g)
#pragma unroll
    for (int s = 0; s < 16; ++s)
      bfr[g][s] = *(const short8*)
          &wht[(size_t)(g * 512 + i0 + l16) * 512 + s * 32 + q * 8];

  const int dim = i0 + l16;        // C-layout col
  const float bhn_c = bhn[dim];
  const int bc0 = w * 16 + q * 4;  // C-layout rows (batches) bc0..bc0+3
  const int ba = w * 16 + l16;     // A-frag row (batch)

  float hreg[4];
#pragma unroll
  for (int r = 0; r < 4; ++r) hreg[r] = h0[(size_t)(bc0 + r) * 512 + dim];

  float xgv[3][4];                 // step-t xg values (prefetched)
#pragma unroll
  for (int r = 0; r < 4; ++r) {
    size_t xb = (size_t)(bc0 + r) * 1536 + dim;
    xgv[0][r] = bf2f(xg[xb]);
    xgv[1][r] = bf2f(xg[xb + 512]);
    xgv[2][r] = bf2f(xg[xb + 1024]);
  }

  for (int t = 0; t < 1024; ++t) {
    const unsigned short* hsrc = hbf + (size_t)(t & 1) * 32768;
    unsigned short* hdst = hbf + (size_t)((t + 1) & 1) * 32768;

    // A-frags via agent-scope loads (LLC-coherent, bypass stale L1/L2)
    short8 af[16];
#pragma unroll
    for (int s = 0; s < 16; ++s)
      af[s] = load_frag_agent(&hsrc[(size_t)ba * 512 + s * 32 + q * 8]);

    floatx4 a0 = {0.f, 0.f, 0.f, 0.f};
    floatx4 a1 = {0.f, 0.f, 0.f, 0.f};
    floatx4 a2 = {0.f, 0.f, 0.f, 0.f};
#pragma unroll
    for (int s = 0; s < 16; ++s) {
      a0 = __builtin_amdgcn_mfma_f32_16x16x32_bf16(af[s], bfr[0][s], a0, 0, 0, 0);
      a1 = __builtin_amdgcn_mfma_f32_16x16x32_bf16(af[s], bfr[1][s], a1, 0, 0, 0);
      a2 = __builtin_amdgcn_mfma_f32_16x16x32_bf16(af[s], bfr[2][s], a2, 0, 0, 0);
    }

#pragma unroll
    for (int r = 0; r < 4; ++r) {
      const int bc = bc0 + r;
      float rg = 1.f / (1.f + __expf(-(xgv[0][r] + a0[r])));
      float zg = 1.f / (1.f + __expf(-(xgv[1][r] + a1[r])));
      float pre = xgv[2][r] + rg * (a2[r] + bhn_c);
      pre = fminf(fmaxf(pre, -15.f), 15.f);  // avoid inf/inf NaN in tanh
      float e2 = __expf(2.f * pre);
      float ng = (e2 - 1.f) / (e2 + 1.f);
      float hnew = (1.f - zg) * ng + zg * hreg[r];
      hreg[r] = hnew;
      // h exchange: agent-scope store (write-through to LLC, sc1)
      __hip_atomic_store(&hdst[(size_t)bc * 512 + dim], f2bf(hnew),
                         __ATOMIC_RELAXED, __HIP_MEMORY_SCOPE_AGENT);
      ys[((size_t)t * 64 + bc) * 512 + dim] = hnew;
    }

    if (t != 1023) {
      // prefetch next-step xg: no h dependence, hides behind the barrier
#pragma unroll
      for (int r = 0; r < 4; ++r) {
        size_t xb = ((size_t)(t + 1) * 64 + bc0 + r) * 1536 + dim;
        xgv[0][r] = bf2f(xg[xb]);
        xgv[1][r] = bf2f(xg[xb + 512]);
        xgv[2][r] = bf2f(xg[xb + 1024]);
      }
      __syncthreads();  // drains vmcnt: all sc1 h-stores are in the LLC
      if (tid == 0) {
        __hip_atomic_fetch_add(ctr, 1u, __ATOMIC_RELAXED,
                               __HIP_MEMORY_SCOPE_AGENT);
        const unsigned tgt = (unsigned)NB * (unsigned)(t + 1);
        while (__hip_atomic_load(ctr, __ATOMIC_RELAXED,
                                 __HIP_MEMORY_SCOPE_AGENT) < tgt) {}
      }
      __syncthreads();
    }
  }
}

extern "C" void kernel_launch(void* const* d_in, const int* in_sizes, int n_in,
                              void* d_out, int out_size, void* d_ws, size_t ws_size,
                              hipStream_t stream) {
  const float* x   = (const float*)d_in[0];
  const float* h0  = (const float*)d_in[1];
  const float* Wi  = (const float*)d_in[2];
  const float* bi  = (const float*)d_in[3];
  const float* Wh  = (const float*)d_in[4];
  const float* bhn = (const float*)d_in[5];
  float* ys = (float*)d_out;

  char* ws = (char*)d_ws;
  unsigned short* xg  = (unsigned short*)(ws);
  unsigned short* xbf = (unsigned short*)(ws + 201326592);
  unsigned short* wit = (unsigned short*)(ws + 234881024);
  unsigned short* wht = (unsigned short*)(ws + 235667456);
  unsigned short* hbf = (unsigned short*)(ws + 237240320);
  unsigned int*   ctr = (unsigned int*)(ws + 237371392);

  prep_kernel<<<21121, 256, 0, stream>>>(x, h0, Wi, Wh, xbf, wit, wht, hbf, ctr);
  gemm_xg<<<dim3(512, 12), 256, 0, stream>>>(xbf, wit, bi, xg);
  scan_kernel<<<NB, 256, 0, stream>>>(xg, wht, h0, bhn, ys, hbf, ctr);
}